// Round 2
// 513.348 us; speedup vs baseline: 1.1116x; 1.1116x over previous
//
#include <hip/hip_runtime.h>
#include <stdint.h>

// GGUF Q8_0-style quantized linear: C[M,N] = A[M,K] * W[K,N] + bias[N]
//   W[k][n] = q[k][n] * scales[k][n>>5]
// M = 8192, K = 4096, N = 4096.
//
// Three-kernel strategy:
//   pass 1a: A fp32 -> bf16 (workspace)
//   pass 1b: dequant + transpose W -> Wt[N][K] bf16 (workspace)
//   pass 2:  256x256-tile bf16 MFMA GEMM, BK=32, 4-slot LDS ring,
//            global_load_lds prefetch 3 tiles deep, raw s_barrier +
//            counted s_waitcnt vmcnt(8) (never 0 in main loop),
//            XOR chunk swizzle (source+read involution), setprio(1) on MFMA,
//            XCD-aware block swizzle.

#define M_DIM 8192
#define N_DIM 4096
#define K_DIM 4096
#define NBLK  128   // N / 32
#define NT    128   // K / BK, BK = 32

typedef __attribute__((ext_vector_type(8))) short short8;   // 8 bf16
typedef __attribute__((ext_vector_type(4))) float f32x4;

typedef const __attribute__((address_space(1))) unsigned char* gas;
typedef __attribute__((address_space(3))) unsigned char* las;

// Pack two fp32 into two bf16 (RNE): low = a, high = b.
__device__ __forceinline__ unsigned pk_bf16(float a, float b) {
  unsigned ua = __builtin_bit_cast(unsigned, a);
  unsigned ub = __builtin_bit_cast(unsigned, b);
  ua += 0x7fffu + ((ua >> 16) & 1u);
  ub += 0x7fffu + ((ub >> 16) & 1u);
  return (ua >> 16) | (ub & 0xffff0000u);
}

// ---------------- pass 1a: A fp32 -> bf16 ----------------
__global__ __launch_bounds__(256)
void a_to_bf16(const float* __restrict__ A, ushort* __restrict__ Abf) {
  const long idx = ((long)blockIdx.x * 256 + threadIdx.x) * 8;
  const float4 v0 = *(const float4*)(A + idx);
  const float4 v1 = *(const float4*)(A + idx + 4);
  uint4 p;
  p.x = pk_bf16(v0.x, v0.y);
  p.y = pk_bf16(v0.z, v0.w);
  p.z = pk_bf16(v1.x, v1.y);
  p.w = pk_bf16(v1.z, v1.w);
  *(uint4*)(Abf + idx) = p;
}

// ------- pass 1b: dequant + transpose: Q[K][N] -> Wt[N][K] bf16 -------
__global__ __launch_bounds__(256)
void dequant_transpose(const int* __restrict__ Q, const float* __restrict__ S,
                       ushort* __restrict__ Wt) {
  __shared__ ushort T[64 * 68];
  const int k0 = blockIdx.y * 64;
  const int n0 = blockIdx.x * 64;
  const int t = threadIdx.x;
  const int nl = t & 63;        // lane-over-n: coalesced Q reads
  const int kb = t >> 6;        // 0..3

  #pragma unroll
  for (int i = 0; i < 16; ++i) {
    const int kl = kb + i * 4;
    const int k = k0 + kl;
    const int q = Q[(long)k * N_DIM + n0 + nl];
    const float s = S[k * NBLK + ((n0 + nl) >> 5)];
    const float w = (float)q * s;
    unsigned u = __builtin_bit_cast(unsigned, w);
    u += 0x7fffu + ((u >> 16) & 1u);
    T[nl * 68 + kl] = (ushort)(u >> 16);
  }
  __syncthreads();

  const int n = t >> 2;             // 0..63
  const int kc = (t & 3) * 16;      // 0,16,32,48
  const ushort* src = &T[n * 68 + kc];
  uint2 a = *(const uint2*)(src + 0);
  uint2 b = *(const uint2*)(src + 4);
  uint2 c = *(const uint2*)(src + 8);
  uint2 d = *(const uint2*)(src + 12);
  uint4 o0 = {a.x, a.y, b.x, b.y};
  uint4 o1 = {c.x, c.y, d.x, d.y};
  ushort* dst = Wt + (long)(n0 + n) * K_DIM + k0 + kc;
  *(uint4*)(dst + 0) = o0;
  *(uint4*)(dst + 8) = o1;
}

// ---------------- pass 2: 256x256 counted-vmcnt GEMM ----------------
// A[M][K] bf16, Wt[N][K] bf16 (B^T), C[M][N] fp32 += bias.
// 8 waves (2M x 4N), per-wave 128x64 output = acc[8][4] of 16x16 frags.
// LDS: 4-slot ring, slot = tile & 3; each slot = A[256][32] + B[256][32] bf16
// (16 KiB + 16 KiB), total 128 KiB. Stage runs 3 tiles ahead; the
// end-of-iter vmcnt(8) retires exactly the next tile's 4 loads/thread.
//
// Swizzle (both-sides involution, rule #21): 16B k-chunk c at LDS row r
// holds global chunk c ^ ((r>>1)&3). Staging lane l (row base+(l>>2),
// chunk l&3) loads global chunk (l&3)^((l>>3)&3); reader at row R wanting
// chunk q reads LDS chunk q^((R>>1)&3). Spreads a wave's 64 ds_read_b128
// lanes perfectly over the 8 (parity x chunk) bank-sets.
__global__ __launch_bounds__(512, 2)
void gemm256(const ushort* __restrict__ Abf, const ushort* __restrict__ Wt,
             const float* __restrict__ bias, float* __restrict__ C) {
  __shared__ __align__(16) ushort lds[4 * 16384];   // 128 KiB

  const int tid = threadIdx.x;
  const int wave = tid >> 6, lane = tid & 63;
  const int lrow = lane & 15, quad = lane >> 4;

  // XCD-aware swizzle: 512 blocks, 512 % 8 == 0 -> simple bijection.
  int id = (int)blockIdx.x;
  id = (id & 7) * 64 + (id >> 3);
  const int m0 = (id >> 4) * 256;    // 32 M-tiles
  const int n0 = (id & 15) * 256;    // 16 N-tiles

  const int wm = (wave >> 2) * 128;  // 2 M-halves
  const int wn = (wave & 3) * 64;    // 4 N-quarters
  const int rchunk = (quad ^ ((lrow >> 1) & 3)) * 8;   // read-side swizzle

  // Staging source (inverse-swizzled global address, linear LDS dest).
  const int srow = lane >> 2;                              // 0..15
  const int schunk = ((lane & 3) ^ ((lane >> 3) & 3)) * 8; // src-side swizzle
  const ushort* Ag0 = Abf + (long)(m0 + wave * 16 + srow) * K_DIM + schunk;
  const ushort* Ag1 = Ag0 + (long)128 * K_DIM;
  const ushort* Bg0 = Wt  + (long)(n0 + wave * 16 + srow) * K_DIM + schunk;
  const ushort* Bg1 = Bg0 + (long)128 * K_DIM;

  f32x4 acc[8][4];
  #pragma unroll
  for (int i = 0; i < 8; ++i)
    #pragma unroll
    for (int j = 0; j < 4; ++j)
      acc[i][j] = (f32x4){0.f, 0.f, 0.f, 0.f};

#define STAGE(kt, ss) do {                                                   \
    const long ko_ = (long)(kt) * 32;                                        \
    ushort* As_ = (ushort*)&lds[(ss) * 16384];                               \
    __builtin_amdgcn_global_load_lds((gas)(Ag0 + ko_),                       \
        (las)(As_ + wave * 512), 16, 0, 0);                                  \
    __builtin_amdgcn_global_load_lds((gas)(Ag1 + ko_),                       \
        (las)(As_ + 4096 + wave * 512), 16, 0, 0);                           \
    __builtin_amdgcn_global_load_lds((gas)(Bg0 + ko_),                       \
        (las)(As_ + 8192 + wave * 512), 16, 0, 0);                           \
    __builtin_amdgcn_global_load_lds((gas)(Bg1 + ko_),                       \
        (las)(As_ + 12288 + wave * 512), 16, 0, 0);                          \
  } while (0)

#define COMPUTE(s_) do {                                                     \
    const ushort* As_ = (const ushort*)&lds[(s_) * 16384];                   \
    const ushort* Bs_ = As_ + 8192;                                          \
    short8 af[8], bf[4];                                                     \
    _Pragma("unroll")                                                        \
    for (int mt = 0; mt < 8; ++mt)                                           \
      af[mt] = *(const short8*)&As_[(wm + mt * 16 + lrow) * 32 + rchunk];    \
    _Pragma("unroll")                                                        \
    for (int nt2 = 0; nt2 < 4; ++nt2)                                        \
      bf[nt2] = *(const short8*)&Bs_[(wn + nt2 * 16 + lrow) * 32 + rchunk];  \
    __builtin_amdgcn_s_setprio(1);                                           \
    _Pragma("unroll")                                                        \
    for (int mt = 0; mt < 8; ++mt)                                           \
      _Pragma("unroll")                                                      \
      for (int nt2 = 0; nt2 < 4; ++nt2)                                      \
        acc[mt][nt2] = __builtin_amdgcn_mfma_f32_16x16x32_bf16(              \
            af[mt], bf[nt2], acc[mt][nt2], 0, 0, 0);                         \
    __builtin_amdgcn_s_setprio(0);                                           \
  } while (0)

#define SYNC(n_) do {                                                        \
    asm volatile("s_waitcnt vmcnt(" #n_ ")" ::: "memory");                   \
    __builtin_amdgcn_s_barrier();                                            \
    __builtin_amdgcn_sched_barrier(0);                                       \
  } while (0)

  // Prologue: 3 tiles in flight; vmcnt(8) retires tile 0 (oldest 4/thread).
  STAGE(0, 0);
  STAGE(1, 1);
  STAGE(2, 2);
  SYNC(8);

  // Main loop: stage tile t+3 into slot (t+3)&3 (last read at iter t-1,
  // protected by that iter's barrier); compute tile t; vmcnt(8) retires
  // tile t+1's loads; barrier publishes them to all waves.
  #pragma unroll 1
  for (int t = 0; t < NT - 4; t += 4) {
    STAGE(t + 3, 3); COMPUTE(0); SYNC(8);
    STAGE(t + 4, 0); COMPUTE(1); SYNC(8);
    STAGE(t + 5, 1); COMPUTE(2); SYNC(8);
    STAGE(t + 6, 2); COMPUTE(3); SYNC(8);
  }
  // Tail: tiles 124..127. Outstanding drains 12 -> 8 -> 4 -> 0.
  STAGE(127, 3); COMPUTE(0); SYNC(8);
  COMPUTE(1); SYNC(4);
  COMPUTE(2); SYNC(0);
  COMPUTE(3);

#undef STAGE
#undef COMPUTE
#undef SYNC

  // Epilogue: C/D layout row = quad*4 + reg, col = lane&15 (verified).
  #pragma unroll
  for (int nt2 = 0; nt2 < 4; ++nt2) {
    const int n = n0 + wn + nt2 * 16 + lrow;
    const float bv = bias[n];
    #pragma unroll
    for (int mt = 0; mt < 8; ++mt) {
      const int mbase = m0 + wm + mt * 16 + quad * 4;
      #pragma unroll
      for (int r = 0; r < 4; ++r)
        C[(long)(mbase + r) * N_DIM + n] = acc[mt][nt2][r] + bv;
    }
  }
}

// ---------------- fallback (round-1 fused kernel) ----------------
__global__ __launch_bounds__(256)
void gguf_gemm_fused(const float* __restrict__ A, const int* __restrict__ Q,
                     const float* __restrict__ S, const float* __restrict__ bias,
                     float* __restrict__ C) {
  __shared__ __align__(16) ushort Alds[128 * 32];
  __shared__ __align__(16) ushort Blds[128 * 32];
  const int tid = threadIdx.x;
  const int m0 = blockIdx.y * 128;
  const int n0 = blockIdx.x * 128;
  const int wave = tid >> 6, lane = tid & 63;
  const int wm = (wave >> 1) * 64, wn = (wave & 1) * 64;
  const int lrow = lane & 15, quad = lane >> 4;
  const int ar = tid >> 2, ac = (tid & 3) * 4;
  const int c8a = ((ar >> 1) & 3) << 3;
  const int bn = tid & 127, bkc = (tid >> 7) * 16;
  const int c8b = ((bn >> 1) & 3) << 3;
  const float* Abase = A + (long)(m0 + ar) * K_DIM + ac;
  const int* Qbase = Q + (long)bkc * N_DIM + n0 + bn;
  const float* Sbase = S + (long)bkc * NBLK + ((n0 + bn) >> 5);
  f32x4 acc[4][4];
  #pragma unroll
  for (int i = 0; i < 4; ++i)
    #pragma unroll
    for (int j = 0; j < 4; ++j) acc[i][j] = (f32x4){0.f, 0.f, 0.f, 0.f};
  for (int k0 = 0; k0 < K_DIM; k0 += 32) {
    #pragma unroll
    for (int i = 0; i < 2; ++i)
      #pragma unroll
      for (int j = 0; j < 2; ++j) {
        const float4 v = *(const float4*)(Abase + (long)i * 64 * K_DIM + k0 + j * 16);
        uint2 p; p.x = pk_bf16(v.x, v.y); p.y = pk_bf16(v.z, v.w);
        const int k = ac + j * 16;
        *(uint2*)&Alds[(ar + i * 64) * 32 + (k ^ c8a)] = p;
      }
    {
      const int* qp = Qbase + (long)k0 * N_DIM;
      const float* sp = Sbase + (long)k0 * NBLK;
      unsigned w[8];
      #pragma unroll
      for (int i = 0; i < 8; ++i) {
        const int q0 = qp[(2 * i) * N_DIM];
        const int q1 = qp[(2 * i + 1) * N_DIM];
        const float s0 = sp[(2 * i) * NBLK];
        const float s1 = sp[(2 * i + 1) * NBLK];
        w[i] = pk_bf16((float)q0 * s0, (float)q1 * s1);
      }
      uint4 g0 = {w[0], w[1], w[2], w[3]};
      uint4 g1 = {w[4], w[5], w[6], w[7]};
      *(uint4*)&Blds[bn * 32 + (bkc ^ c8b)] = g0;
      *(uint4*)&Blds[bn * 32 + ((bkc + 8) ^ c8b)] = g1;
    }
    __syncthreads();
    short8 afrag[4], bfrag[4];
    #pragma unroll
    for (int t = 0; t < 4; ++t) {
      const int mrow = wm + t * 16 + lrow;
      afrag[t] = *(const short8*)&Alds[mrow * 32 + ((quad * 8) ^ (((mrow >> 1) & 3) << 3))];
      const int nrow = wn + t * 16 + lrow;
      bfrag[t] = *(const short8*)&Blds[nrow * 32 + ((quad * 8) ^ (((nrow >> 1) & 3) << 3))];
    }
    #pragma unroll
    for (int mt = 0; mt < 4; ++mt)
      #pragma unroll
      for (int nt = 0; nt < 4; ++nt)
        acc[mt][nt] = __builtin_amdgcn_mfma_f32_16x16x32_bf16(afrag[mt], bfrag[nt],
                                                              acc[mt][nt], 0, 0, 0);
    __syncthreads();
  }
  #pragma unroll
  for (int nt = 0; nt < 4; ++nt) {
    const int n = n0 + wn + nt * 16 + lrow;
    const float bv = bias[n];
    #pragma unroll
    for (int mt = 0; mt < 4; ++mt) {
      const int mbase = m0 + wm + mt * 16 + quad * 4;
      #pragma unroll
      for (int r = 0; r < 4; ++r)
        C[(long)(mbase + r) * N_DIM + n] = acc[mt][nt][r] + bv;
    }
  }
}

extern "C" void kernel_launch(void* const* d_in, const int* in_sizes, int n_in,
                              void* d_out, int out_size, void* d_ws, size_t ws_size,
                              hipStream_t stream) {
  const float* A    = (const float*)d_in[0];
  const int*   Q    = (const int*)d_in[1];
  const float* S    = (const float*)d_in[2];
  const float* bias = (const float*)d_in[3];
  float* C = (float*)d_out;

  const size_t abf_bytes = (size_t)M_DIM * K_DIM * 2;   // 64 MiB
  const size_t wt_bytes  = (size_t)N_DIM * K_DIM * 2;   // 32 MiB

  if (ws_size >= abf_bytes + wt_bytes) {
    ushort* Abf = (ushort*)d_ws;
    ushort* Wt  = (ushort*)((char*)d_ws + abf_bytes);
    a_to_bf16<<<(M_DIM * (long)K_DIM) / (256 * 8), 256, 0, stream>>>(A, Abf);
    dim3 gt(N_DIM / 64, K_DIM / 64);
    dequant_transpose<<<gt, 256, 0, stream>>>(Q, S, Wt);
    gemm256<<<dim3((M_DIM / 256) * (N_DIM / 256)), dim3(512), 0, stream>>>(Abf, Wt, bias, C);
  } else {
    dim3 grid(N_DIM / 128, M_DIM / 128);
    gguf_gemm_fused<<<grid, 256, 0, stream>>>(A, Q, S, bias, C);
  }
}

// Round 4
// 496.768 us; speedup vs baseline: 1.1487x; 1.0334x over previous
//
#include <hip/hip_runtime.h>
#include <stdint.h>

// GGUF Q8_0-style quantized linear: C[M,N] = A[M,K] * W[K,N] + bias[N]
//   W[k][n] = q[k][n] * scales[k][n>>5]
// M = 8192, K = 4096, N = 4096.
//
// Three-kernel strategy:
//   pass 1a: A fp32 -> bf16 (workspace)
//   pass 1b: dequant + transpose W -> Wt[N][K] bf16 (workspace)
//   pass 2:  256x256-tile bf16 MFMA GEMM, BK=32, 4-slot LDS ring,
//            3-tile-deep global_load_lds prefetch, counted vmcnt(8),
//            TWO fine phases per K-tile (m201-style interleave:
//            {ds_read || stage-issue -> bar -> lgkm(0) -> 16 MFMA -> bar}),
//            XOR chunk swizzle (source+read involution), setprio(1) on MFMA,
//            XCD-aware 8m x 4n chunked block swizzle.
//
// Round-3 bug (NaN): STAGE_B wrote B-half at slot+16384 ushorts (units slip,
// bytes-vs-ushorts) = next slot's A region / OOB for slot 3. Fixed: +8192.

#define M_DIM 8192
#define N_DIM 4096
#define K_DIM 4096
#define NBLK  128   // N / 32
#define NT    128   // K / BK, BK = 32

typedef __attribute__((ext_vector_type(8))) short short8;   // 8 bf16
typedef __attribute__((ext_vector_type(4))) float f32x4;

typedef const __attribute__((address_space(1))) unsigned char* gas;
typedef __attribute__((address_space(3))) unsigned char* las;

// Pack two fp32 into two bf16 (RNE): low = a, high = b.
__device__ __forceinline__ unsigned pk_bf16(float a, float b) {
  unsigned ua = __builtin_bit_cast(unsigned, a);
  unsigned ub = __builtin_bit_cast(unsigned, b);
  ua += 0x7fffu + ((ua >> 16) & 1u);
  ub += 0x7fffu + ((ub >> 16) & 1u);
  return (ua >> 16) | (ub & 0xffff0000u);
}

// ---------------- pass 1a: A fp32 -> bf16 ----------------
__global__ __launch_bounds__(256)
void a_to_bf16(const float* __restrict__ A, ushort* __restrict__ Abf) {
  const long idx = ((long)blockIdx.x * 256 + threadIdx.x) * 8;
  const float4 v0 = *(const float4*)(A + idx);
  const float4 v1 = *(const float4*)(A + idx + 4);
  uint4 p;
  p.x = pk_bf16(v0.x, v0.y);
  p.y = pk_bf16(v0.z, v0.w);
  p.z = pk_bf16(v1.x, v1.y);
  p.w = pk_bf16(v1.z, v1.w);
  *(uint4*)(Abf + idx) = p;
}

// ------- pass 1b: dequant + transpose: Q[K][N] -> Wt[N][K] bf16 -------
__global__ __launch_bounds__(256)
void dequant_transpose(const int* __restrict__ Q, const float* __restrict__ S,
                       ushort* __restrict__ Wt) {
  __shared__ ushort T[64 * 68];
  const int k0 = blockIdx.y * 64;
  const int n0 = blockIdx.x * 64;
  const int t = threadIdx.x;
  const int nl = t & 63;        // lane-over-n: coalesced Q reads
  const int kb = t >> 6;        // 0..3

  #pragma unroll
  for (int i = 0; i < 16; ++i) {
    const int kl = kb + i * 4;
    const int k = k0 + kl;
    const int q = Q[(long)k * N_DIM + n0 + nl];
    const float s = S[k * NBLK + ((n0 + nl) >> 5)];
    const float w = (float)q * s;
    unsigned u = __builtin_bit_cast(unsigned, w);
    u += 0x7fffu + ((u >> 16) & 1u);
    T[nl * 68 + kl] = (ushort)(u >> 16);
  }
  __syncthreads();

  const int n = t >> 2;             // 0..63
  const int kc = (t & 3) * 16;      // 0,16,32,48
  const ushort* src = &T[n * 68 + kc];
  uint2 a = *(const uint2*)(src + 0);
  uint2 b = *(const uint2*)(src + 4);
  uint2 c = *(const uint2*)(src + 8);
  uint2 d = *(const uint2*)(src + 12);
  uint4 o0 = {a.x, a.y, b.x, b.y};
  uint4 o1 = {c.x, c.y, d.x, d.y};
  ushort* dst = Wt + (long)(n0 + n) * K_DIM + k0 + kc;
  *(uint4*)(dst + 0) = o0;
  *(uint4*)(dst + 8) = o1;
}

// ---------------- pass 2: 256x256 counted-vmcnt GEMM, 2-phase tiles -------
// A[M][K] bf16, Wt[N][K] bf16 (B^T), C[M][N] fp32 += bias.
// 8 waves (2M x 4N), per-wave 128x64 output = acc[8][4] of 16x16 frags.
// LDS: 4-slot ring, slot = tile & 3; each slot = A[256][32] + B[256][32]
// (32 KiB), total 128 KiB. Stage runs 3 tiles ahead; vmcnt(8) once per
// tile retires exactly the next tile's 4 loads/thread. Per tile, two
// phases of 16 MFMA each; phase A issues the A-half stage, phase B the
// B-half stage + the vmcnt(8) publish.
//
// Swizzle (both-sides involution): 16B k-chunk c at LDS row r holds global
// chunk c ^ ((r>>1)&3). Staging lane l (row base+(l>>2), chunk l&3) loads
// global chunk (l&3)^((l>>3)&3); reader at row R wanting chunk q reads LDS
// chunk q^((R>>1)&3). Zero bank conflicts (verified round 2: counter = 0).
__global__ __launch_bounds__(512, 2)
void gemm256(const ushort* __restrict__ Abf, const ushort* __restrict__ Wt,
             const float* __restrict__ bias, float* __restrict__ C) {
  __shared__ __align__(16) ushort lds[4 * 16384];   // 128 KiB

  const int tid = threadIdx.x;
  const int wave = tid >> 6, lane = tid & 63;
  const int lrow = lane & 15, quad = lane >> 4;

  // XCD-aware chunked swizzle: block b lands on XCD b%8 (dispatch
  // round-robin). Give XCD x an 8m x 8n tile chunk, traversed m-fastest so
  // the 32 concurrently-resident blocks cover 8m x 4n (24 MB working set).
  const int id = (int)blockIdx.x;
  const int xcd = id & 7;
  const int j = id >> 3;                  // 0..63 within chunk
  const int m0 = ((xcd & 3) * 8 + (j & 7)) * 256;   // 32 m-tiles
  const int n0 = ((xcd >> 2) * 8 + (j >> 3)) * 256; // 16 n-tiles

  const int wm = (wave >> 2) * 128;  // 2 M-halves
  const int wn = (wave & 3) * 64;    // 4 N-quarters
  const int rchunk = (quad ^ ((lrow >> 1) & 3)) * 8;   // read-side swizzle

  // Staging source (inverse-swizzled global address, linear LDS dest).
  const int srow = lane >> 2;                              // 0..15
  const int schunk = ((lane & 3) ^ ((lane >> 3) & 3)) * 8; // src-side swizzle
  const ushort* Ag0 = Abf + (long)(m0 + wave * 16 + srow) * K_DIM + schunk;
  const ushort* Ag1 = Ag0 + (long)128 * K_DIM;
  const ushort* Bg0 = Wt  + (long)(n0 + wave * 16 + srow) * K_DIM + schunk;
  const ushort* Bg1 = Bg0 + (long)128 * K_DIM;

  f32x4 acc[8][4];
  #pragma unroll
  for (int i = 0; i < 8; ++i)
    #pragma unroll
    for (int j2 = 0; j2 < 4; ++j2)
      acc[i][j2] = (f32x4){0.f, 0.f, 0.f, 0.f};

#define STAGE_A(kt, ss) do {                                                 \
    const long koa_ = (long)(kt) * 32;                                       \
    ushort* Ad_ = (ushort*)&lds[(ss) * 16384];                               \
    __builtin_amdgcn_global_load_lds((gas)(Ag0 + koa_),                      \
        (las)(Ad_ + wave * 512), 16, 0, 0);                                  \
    __builtin_amdgcn_global_load_lds((gas)(Ag1 + koa_),                      \
        (las)(Ad_ + 4096 + wave * 512), 16, 0, 0);                           \
  } while (0)

// B-half lands at slot base + 8192 ushorts (16 KiB) — matches read side.
#define STAGE_B(kt, ss) do {                                                 \
    const long kob_ = (long)(kt) * 32;                                       \
    ushort* Bd_ = (ushort*)&lds[(ss) * 16384 + 8192];                        \
    __builtin_amdgcn_global_load_lds((gas)(Bg0 + kob_),                      \
        (las)(Bd_ + wave * 512), 16, 0, 0);                                  \
    __builtin_amdgcn_global_load_lds((gas)(Bg1 + kob_),                      \
        (las)(Bd_ + 4096 + wave * 512), 16, 0, 0);                           \
  } while (0)

#define VM8 asm volatile("s_waitcnt vmcnt(8)" ::: "memory")
#define VM4 asm volatile("s_waitcnt vmcnt(4)" ::: "memory")
#define VM0 asm volatile("s_waitcnt vmcnt(0)" ::: "memory")
#define NOP ((void)0)

// One K-tile = two phases. SA_/SB_ are stage statements (or NOP); VMW_ is
// the per-tile publish wait (or NOP). Hazards: tile t's slot was published
// by tile t-1's mid-phase-B {vmcnt(8); barrier}; stage into slot (t+3)&3
// == (t-1)&3 issues after tile t-1's end barrier, behind every wave's
// lgkmcnt(0)-drained reads of that slot.
#define TILE(s_, SA_, SB_, VMW_) do {                                        \
    const ushort* Asl_ = (const ushort*)&lds[(s_) * 16384];                  \
    const ushort* Bsl_ = Asl_ + 8192;                                        \
    short8 af_[4], a2_[4], bf_[4];                                           \
    _Pragma("unroll")                                                        \
    for (int mt = 0; mt < 4; ++mt)                                           \
      af_[mt] = *(const short8*)&Asl_[(wm + mt * 16 + lrow) * 32 + rchunk];  \
    _Pragma("unroll")                                                        \
    for (int nt2 = 0; nt2 < 4; ++nt2)                                        \
      bf_[nt2] = *(const short8*)&Bsl_[(wn + nt2 * 16 + lrow) * 32 + rchunk];\
    SA_;                                                                     \
    __builtin_amdgcn_s_barrier();                                            \
    asm volatile("s_waitcnt lgkmcnt(0)" ::: "memory");                       \
    __builtin_amdgcn_sched_barrier(0);                                       \
    __builtin_amdgcn_s_setprio(1);                                           \
    _Pragma("unroll")                                                        \
    for (int mt = 0; mt < 4; ++mt)                                           \
      _Pragma("unroll")                                                      \
      for (int nt2 = 0; nt2 < 4; ++nt2)                                      \
        acc[mt][nt2] = __builtin_amdgcn_mfma_f32_16x16x32_bf16(              \
            af_[mt], bf_[nt2], acc[mt][nt2], 0, 0, 0);                       \
    __builtin_amdgcn_s_setprio(0);                                           \
    __builtin_amdgcn_s_barrier();                                            \
    _Pragma("unroll")                                                        \
    for (int mt = 0; mt < 4; ++mt)                                           \
      a2_[mt] = *(const short8*)&Asl_[(wm + 64 + mt * 16 + lrow) * 32 + rchunk]; \
    SB_;                                                                     \
    VMW_;                                                                    \
    __builtin_amdgcn_s_barrier();                                            \
    asm volatile("s_waitcnt lgkmcnt(0)" ::: "memory");                       \
    __builtin_amdgcn_sched_barrier(0);                                       \
    __builtin_amdgcn_s_setprio(1);                                           \
    _Pragma("unroll")                                                        \
    for (int mt = 0; mt < 4; ++mt)                                           \
      _Pragma("unroll")                                                      \
      for (int nt2 = 0; nt2 < 4; ++nt2)                                      \
        acc[mt + 4][nt2] = __builtin_amdgcn_mfma_f32_16x16x32_bf16(          \
            a2_[mt], bf_[nt2], acc[mt + 4][nt2], 0, 0, 0);                   \
    __builtin_amdgcn_s_setprio(0);                                           \
    __builtin_amdgcn_s_barrier();                                            \
    __builtin_amdgcn_sched_barrier(0);                                       \
  } while (0)

  // Prologue: 3 tiles in flight (12 loads/thread); vmcnt(8) retires tile 0.
  STAGE_A(0, 0); STAGE_B(0, 0);
  STAGE_A(1, 1); STAGE_B(1, 1);
  STAGE_A(2, 2); STAGE_B(2, 2);
  VM8;
  __builtin_amdgcn_s_barrier();
  __builtin_amdgcn_sched_barrier(0);

  // Main loop. Ledger at top of tile t: 8 outstanding (tiles t+1, t+2).
  // Phase A +2 -> 10, phase B +2 -> 12, vmcnt(8) retires tile t+1's 4.
  #pragma unroll 1
  for (int t = 0; t < NT - 4; t += 4) {
    TILE(0, STAGE_A(t + 3, 3), STAGE_B(t + 3, 3), VM8);
    TILE(1, STAGE_A(t + 4, 0), STAGE_B(t + 4, 0), VM8);
    TILE(2, STAGE_A(t + 5, 1), STAGE_B(t + 5, 1), VM8);
    TILE(3, STAGE_A(t + 6, 2), STAGE_B(t + 6, 2), VM8);
  }
  // Tail: tiles 124..127. Outstanding drains 12 -> 8 -> 4 -> 0.
  TILE(0, STAGE_A(127, 3), STAGE_B(127, 3), VM8);
  TILE(1, NOP, NOP, VM4);
  TILE(2, NOP, NOP, VM0);
  TILE(3, NOP, NOP, NOP);

#undef STAGE_A
#undef STAGE_B
#undef TILE
#undef VM8
#undef VM4
#undef VM0
#undef NOP

  // Epilogue: C/D layout row = quad*4 + reg, col = lane&15 (verified).
  #pragma unroll
  for (int nt2 = 0; nt2 < 4; ++nt2) {
    const int n = n0 + wn + nt2 * 16 + lrow;
    const float bv = bias[n];
    #pragma unroll
    for (int mt = 0; mt < 8; ++mt) {
      const int mbase = m0 + wm + mt * 16 + quad * 4;
      #pragma unroll
      for (int r = 0; r < 4; ++r)
        C[(long)(mbase + r) * N_DIM + n] = acc[mt][nt2][r] + bv;
    }
  }
}

// ---------------- fallback (round-1 fused kernel) ----------------
__global__ __launch_bounds__(256)
void gguf_gemm_fused(const float* __restrict__ A, const int* __restrict__ Q,
                     const float* __restrict__ S, const float* __restrict__ bias,
                     float* __restrict__ C) {
  __shared__ __align__(16) ushort Alds[128 * 32];
  __shared__ __align__(16) ushort Blds[128 * 32];
  const int tid = threadIdx.x;
  const int m0 = blockIdx.y * 128;
  const int n0 = blockIdx.x * 128;
  const int wave = tid >> 6, lane = tid & 63;
  const int wm = (wave >> 1) * 64, wn = (wave & 1) * 64;
  const int lrow = lane & 15, quad = lane >> 4;
  const int ar = tid >> 2, ac = (tid & 3) * 4;
  const int c8a = ((ar >> 1) & 3) << 3;
  const int bn = tid & 127, bkc = (tid >> 7) * 16;
  const int c8b = ((bn >> 1) & 3) << 3;
  const float* Abase = A + (long)(m0 + ar) * K_DIM + ac;
  const int* Qbase = Q + (long)bkc * N_DIM + n0 + bn;
  const float* Sbase = S + (long)bkc * NBLK + ((n0 + bn) >> 5);
  f32x4 acc[4][4];
  #pragma unroll
  for (int i = 0; i < 4; ++i)
    #pragma unroll
    for (int j = 0; j < 4; ++j) acc[i][j] = (f32x4){0.f, 0.f, 0.f, 0.f};
  for (int k0 = 0; k0 < K_DIM; k0 += 32) {
    #pragma unroll
    for (int i = 0; i < 2; ++i)
      #pragma unroll
      for (int j = 0; j < 2; ++j) {
        const float4 v = *(const float4*)(Abase + (long)i * 64 * K_DIM + k0 + j * 16);
        uint2 p; p.x = pk_bf16(v.x, v.y); p.y = pk_bf16(v.z, v.w);
        const int k = ac + j * 16;
        *(uint2*)&Alds[(ar + i * 64) * 32 + (k ^ c8a)] = p;
      }
    {
      const int* qp = Qbase + (long)k0 * N_DIM;
      const float* sp = Sbase + (long)k0 * NBLK;
      unsigned w[8];
      #pragma unroll
      for (int i = 0; i < 8; ++i) {
        const int q0 = qp[(2 * i) * N_DIM];
        const int q1 = qp[(2 * i + 1) * N_DIM];
        const float s0 = sp[(2 * i) * NBLK];
        const float s1 = sp[(2 * i + 1) * NBLK];
        w[i] = pk_bf16((float)q0 * s0, (float)q1 * s1);
      }
      uint4 g0 = {w[0], w[1], w[2], w[3]};
      uint4 g1 = {w[4], w[5], w[6], w[7]};
      *(uint4*)&Blds[bn * 32 + (bkc ^ c8b)] = g0;
      *(uint4*)&Blds[bn * 32 + ((bkc + 8) ^ c8b)] = g1;
    }
    __syncthreads();
    short8 afrag[4], bfrag[4];
    #pragma unroll
    for (int t = 0; t < 4; ++t) {
      const int mrow = wm + t * 16 + lrow;
      afrag[t] = *(const short8*)&Alds[mrow * 32 + ((quad * 8) ^ (((mrow >> 1) & 3) << 3))];
      const int nrow = wn + t * 16 + lrow;
      bfrag[t] = *(const short8*)&Blds[nrow * 32 + ((quad * 8) ^ (((nrow >> 1) & 3) << 3))];
    }
    #pragma unroll
    for (int mt = 0; mt < 4; ++mt)
      #pragma unroll
      for (int nt = 0; nt < 4; ++nt)
        acc[mt][nt] = __builtin_amdgcn_mfma_f32_16x16x32_bf16(afrag[mt], bfrag[nt],
                                                              acc[mt][nt], 0, 0, 0);
    __syncthreads();
  }
  #pragma unroll
  for (int nt = 0; nt < 4; ++nt) {
    const int n = n0 + wn + nt * 16 + lrow;
    const float bv = bias[n];
    #pragma unroll
    for (int mt = 0; mt < 4; ++mt) {
      const int mbase = m0 + wm + mt * 16 + quad * 4;
      #pragma unroll
      for (int r = 0; r < 4; ++r)
        C[(long)(mbase + r) * N_DIM + n] = acc[mt][nt][r] + bv;
    }
  }
}

extern "C" void kernel_launch(void* const* d_in, const int* in_sizes, int n_in,
                              void* d_out, int out_size, void* d_ws, size_t ws_size,
                              hipStream_t stream) {
  const float* A    = (const float*)d_in[0];
  const int*   Q    = (const int*)d_in[1];
  const float* S    = (const float*)d_in[2];
  const float* bias = (const float*)d_in[3];
  float* C = (float*)d_out;

  const size_t abf_bytes = (size_t)M_DIM * K_DIM * 2;   // 64 MiB
  const size_t wt_bytes  = (size_t)N_DIM * K_DIM * 2;   // 32 MiB

  if (ws_size >= abf_bytes + wt_bytes) {
    ushort* Abf = (ushort*)d_ws;
    ushort* Wt  = (ushort*)((char*)d_ws + abf_bytes);
    a_to_bf16<<<(M_DIM * (long)K_DIM) / (256 * 8), 256, 0, stream>>>(A, Abf);
    dim3 gt(N_DIM / 64, K_DIM / 64);
    dequant_transpose<<<gt, 256, 0, stream>>>(Q, S, Wt);
    gemm256<<<dim3((M_DIM / 256) * (N_DIM / 256)), dim3(512), 0, stream>>>(Abf, Wt, bias, C);
  } else {
    dim3 grid(N_DIM / 128, M_DIM / 128);
    gguf_gemm_fused<<<grid, 256, 0, stream>>>(A, Q, S, bias, C);
  }
}